// Round 14
// baseline (197.923 us; speedup 1.0000x reference)
//
#include <hip/hip_runtime.h>

// Performer linear attention, 32x32x16 MFMA, register-resident features.
// n=2, l=2048, h=8, e=64, m=2048. Dtype runtime-detected (bf16 confirmed).
// ws (floats): flag[16] | c_k[32768] | c_q[32768] | ksum01[4][32768] | kvf01[4][16][64][2048]
//   f32 | ksumW[32768] | kvT bf16[16][64][2048]
// R20: domain round. Register class caps 16 waves/CU (R14); currently spent as 2 blocks
//     x 8 waves = 2 barrier domains. Rearrange kv/stats as 4 blocks x 4 waves (256-thr):
//     4 independent domains at the same wave/LDS budget -> 2x latency hiding during
//     rendezvous/chains. kv: 128 m-cols/block (16mtb x 16nh x 4sp = 1024 blocks, LDS
//     37.4KBx4=149.5KB); all 256 thr stage K AND V. stats: 64-row blocks, (512,2) grid.
//     out (8-role fused, forced) + reduce unchanged from R19 (best 176.9us).

#define LL 2048
#define HH 8
#define MM 2048
#define ROWSTR 512  // HH*64

#define NORMC 0.35355339059327373f   // 64^-0.25
#define LOG2E 1.4426950408889634f
#define NORMC2 (NORMC * LOG2E)
#define RATIO 0.022097086912079608f  // 2048^-0.5
#define KEPS 1e-4f
#define REPS (RATIO * KEPS)
#define EPSD 1e-6f

#define KVSPLIT 2097152
#define RSPLIT 32768

typedef __attribute__((ext_vector_type(8))) short short8;
typedef __attribute__((ext_vector_type(16))) float f32x16;

#define MFMA32(a, b, c) __builtin_amdgcn_mfma_f32_32x32x16_bf16((a), (b), (c), 0, 0, 0)

// LDS-only workgroup barrier: drains lgkmcnt but leaves global loads in flight.
__device__ __forceinline__ void wg_barrier_lds() {
    asm volatile("s_waitcnt lgkmcnt(0)" ::: "memory");
    __builtin_amdgcn_s_barrier();
    __builtin_amdgcn_sched_barrier(0);
}

__device__ __forceinline__ f32x16 zero16() {
    f32x16 v;
    #pragma unroll
    for (int i = 0; i < 16; ++i) v[i] = 0.f;
    return v;
}
__device__ __forceinline__ unsigned short f2bf(float f) {  // RNE
    union { float f; unsigned int u; } v; v.f = f;
    unsigned int r = v.u + 0x7fffu + ((v.u >> 16) & 1u);
    return (unsigned short)(r >> 16);
}
__device__ __forceinline__ unsigned int pk2(float lo, float hi) {  // trunc pack
    return __builtin_amdgcn_perm(__float_as_uint(hi), __float_as_uint(lo), 0x07060302u);
}
__device__ __forceinline__ float bf2f(unsigned short u) {
    union { unsigned int ui; float f; } v; v.ui = ((unsigned int)u) << 16; return v.f;
}

// ---- direct global row-fragment load: 8 bf16 at row*stride + off ----
template <bool BF16>
__device__ __forceinline__ short8 row_load8(const void* src, size_t rowbase, int off) {
    if (BF16) {
        return *(const short8*)((const unsigned short*)src + rowbase + off);
    } else {
        const float* p = (const float*)src + rowbase + off;
        float4 f0 = ((const float4*)p)[0], f1 = ((const float4*)p)[1];
        union { unsigned int u[4]; short8 s; } v;
        v.u[0] = pk2(f0.x, f0.y); v.u[1] = pk2(f0.z, f0.w);
        v.u[2] = pk2(f1.x, f1.y); v.u[3] = pk2(f1.z, f1.w);
        return v.s;
    }
}

// ---- 64x64 tile staging into LDS [64][72] bf16 (256-thread pattern) ----
template <bool BF16>
__device__ __forceinline__ void tile_load(const void* src, size_t base, size_t rstride,
                                          int t, uint4& A, uint4& B) {
    const int row = t >> 2, c16 = (t & 3) * 16;
    if (BF16) {
        const unsigned short* p = (const unsigned short*)src + base + (size_t)row * rstride + c16;
        A = *(const uint4*)p;
        B = *(const uint4*)(p + 8);
    } else {
        const float* p = (const float*)src + base + (size_t)row * rstride + c16;
        float4 f0 = ((const float4*)p)[0], f1 = ((const float4*)p)[1];
        float4 f2 = ((const float4*)p)[2], f3 = ((const float4*)p)[3];
        A.x = pk2(f0.x, f0.y); A.y = pk2(f0.z, f0.w);
        A.z = pk2(f1.x, f1.y); A.w = pk2(f1.z, f1.w);
        B.x = pk2(f2.x, f2.y); B.y = pk2(f2.z, f2.w);
        B.z = pk2(f3.x, f3.y); B.w = pk2(f3.z, f3.w);
    }
}
__device__ __forceinline__ void tile_store72(unsigned short* D, int t, uint4 A, uint4 B) {
    const int row = t >> 2, c16 = (t & 3) * 16;
    *(uint4*)&D[row * 72 + c16] = A;
    *(uint4*)&D[row * 72 + c16 + 8] = B;
}

// ---- V transpose staging into LDS [64e][72] (256-thread pattern) ----
template <bool BF16>
__device__ __forceinline__ void vt_load(const void* V, size_t base, int t, uint4& A, uint4& B) {
    const int s0 = (t & 31) * 2, e0 = (t >> 5) * 8;
    if (BF16) {
        const unsigned short* p = (const unsigned short*)V + base + (size_t)s0 * ROWSTR + e0;
        A = *(const uint4*)p;
        B = *(const uint4*)(p + ROWSTR);
    } else {
        const float* p = (const float*)V + base + (size_t)s0 * ROWSTR + e0;
        float4 f0 = ((const float4*)p)[0], f1 = ((const float4*)p)[1];
        const float* q = p + ROWSTR;
        float4 g0 = ((const float4*)q)[0], g1 = ((const float4*)q)[1];
        A.x = pk2(f0.x, f0.y); A.y = pk2(f0.z, f0.w);
        A.z = pk2(f1.x, f1.y); A.w = pk2(f1.z, f1.w);
        B.x = pk2(g0.x, g0.y); B.y = pk2(g0.z, g0.w);
        B.z = pk2(g1.x, g1.y); B.w = pk2(g1.z, g1.w);
    }
}
__device__ __forceinline__ void vt_store72(unsigned short* VT, int t, uint4 A, uint4 B) {
    const int s0 = (t & 31) * 2, e0 = (t >> 5) * 8;
    const unsigned ua[4] = {A.x, A.y, A.z, A.w}, ub[4] = {B.x, B.y, B.z, B.w};
    #pragma unroll
    for (int i = 0; i < 4; ++i) {
        *(unsigned*)&VT[(e0 + 2 * i) * 72 + s0] = (ua[i] & 0xFFFFu) | (ub[i] << 16);
        *(unsigned*)&VT[(e0 + 2 * i + 1) * 72 + s0] = (ua[i] >> 16) | (ub[i] & 0xFFFF0000u);
    }
}

// ---- D-layout -> B-operand exchange (half-wave) ----
__device__ __forceinline__ short8 xfrag(const unsigned int pd[8], int cp, int hi) {
    const unsigned int s0 = hi ? pd[4 * cp + 0] : pd[4 * cp + 2];
    const unsigned int s1 = hi ? pd[4 * cp + 1] : pd[4 * cp + 3];
    const unsigned int r0 = (unsigned int)__shfl_xor((int)s0, 32);
    const unsigned int r1 = (unsigned int)__shfl_xor((int)s1, 32);
    union { unsigned int u[4]; short8 s; } v;
    v.u[0] = hi ? r0 : pd[4 * cp + 0];
    v.u[1] = hi ? r1 : pd[4 * cp + 1];
    v.u[2] = hi ? pd[4 * cp + 2] : r0;
    v.u[3] = hi ? pd[4 * cp + 3] : r1;
    return v.s;
}

// ---------------- dtype detection ----------------
__global__ void LinearAttention_15985868276494_detect(const unsigned short* __restrict__ P,
                                                      float* __restrict__ flag) {
    if (threadIdx.x == 0) {
        int sane = 1;
        #pragma unroll
        for (int i = 0; i < 16; ++i) {
            const unsigned e = (P[2 * i] >> 7) & 0xFF;
            if (e < 101 || e > 141) sane = 0;
        }
        *flag = sane ? 1.0f : 0.0f;
    }
}

// ---------------- stats: c[nh][l]*log2e, 64 rows/block, 32 P-tile stream ----------------
// 1024 blocks x 256 thr (4 waves), 4 blk/CU = 4 barrier domains. Staggered ph = bid&31.
// Waves: mstrip=w&1, r2=w>>1 (32-row chunk). All 256 thr stage P.
// LDS: Ps[2][4608] shorts | red[128] f32  (18944 B; x4 = 75.8KB).
template <bool BF16>
__device__ void stats_impl(const void* X, const void* P, float* cws, char* smem) {
    unsigned short* Ps = (unsigned short*)smem;        // [2][4608]
    float* red = (float*)(smem + 18432);               // [128]
    const int t = threadIdx.x;
    const int w = t >> 6, ln = t & 31, hi = (t >> 5) & 1;
    const int mstrip = w & 1, r2 = w >> 1;
    const int row_base = blockIdx.x * 64;
    const int ph = blockIdx.x & 31;

    short8 xb[4];
    #pragma unroll
    for (int c = 0; c < 4; ++c)
        xb[c] = row_load8<BF16>(X, (size_t)(row_base + r2 * 32 + ln) * 64, 16 * c + 8 * hi);

    uint4 pA, pB;
    {
        uint4 a0, b0;
        tile_load<BF16>(P, (size_t)(ph * 64) * 64, 64, t, a0, b0);
        tile_store72(Ps, t, a0, b0);
        tile_load<BF16>(P, (size_t)(((ph + 1) & 31) * 64) * 64, 64, t, pA, pB);
    }
    wg_barrier_lds();

    float rmax = -3e38f;
    for (int i = 0; i < 32; ++i) {
        const int cur = i & 1;
        unsigned short* Pc = Ps + cur * 4608;
        f32x16 acc = zero16();
        #pragma unroll
        for (int c = 0; c < 4; ++c) {
            const short8 af = *(const short8*)&Pc[(32 * mstrip + ln) * 72 + 16 * c + 8 * hi];
            acc = MFMA32(af, xb[c], acc);
        }
        if (i + 1 < 32) {
            tile_store72(Ps + (cur ^ 1) * 4608, t, pA, pB);
            if (i + 2 < 32)
                tile_load<BF16>(P, (size_t)(((i + 2 + ph) & 31) * 64) * 64, 64, t, pA, pB);
        }
        #pragma unroll
        for (int r = 0; r < 16; ++r) rmax = fmaxf(rmax, acc[r]);
        wg_barrier_lds();
    }
    rmax = fmaxf(rmax, __shfl_xor(rmax, 32));
    if (hi == 0) red[w * 32 + ln] = rmax;
    float s2 = 0.f;
    if (mstrip == 0) {
        #pragma unroll
        for (int c = 0; c < 4; ++c) {
            union { short8 s; unsigned int u[4]; } uv; uv.s = xb[c];
            #pragma unroll
            for (int i2 = 0; i2 < 4; ++i2) {
                const float lo = bf2f((unsigned short)(uv.u[i2] & 0xFFFF));
                const float hv = bf2f((unsigned short)(uv.u[i2] >> 16));
                s2 = fmaf(lo, lo, s2); s2 = fmaf(hv, hv, s2);
            }
        }
        s2 += __shfl_xor(s2, 32);
    }
    wg_barrier_lds();
    if (mstrip == 0 && hi == 0) {
        const float rm = fmaxf(red[(r2 * 2) * 32 + ln], red[(r2 * 2 + 1) * 32 + ln]);
        const int rg = row_base + r2 * 32 + ln;
        const int n = rg >> 14, l = (rg >> 3) & 2047, h = rg & 7;
        cws[(size_t)((n << 3) | h) * LL + l] =
            (NORMC * rm + (0.5f * NORMC * NORMC) * s2) * LOG2E;
    }
}

__global__ __launch_bounds__(256, 4) void LinearAttention_15985868276494_stats(
        const void* K, const void* Q, const void* P, const float* flag,
        float* c_k, float* c_q) {
    extern __shared__ char smem_st[];
    const void* X = (blockIdx.y == 0) ? K : Q;
    float* cws = (blockIdx.y == 0) ? c_k : c_q;
    if (*flag != 0.f) stats_impl<true>(X, P, cws, smem_st);
    else stats_impl<false>(X, P, cws, smem_st);
}

// ---------------- kv: partial kvf[sp][nh][e][m] f32, ksum01 (sp in 0..3) ----------------
// 1024 blocks x 256 thr (4 waves), 4 blk/CU = 4 barrier domains. Block owns 128 m-cols;
// streams 8 K/V s-tiles, staggered ph = mtb&7. Decode: xcd=bid&7, rr=bid>>3, gq=rr>>4,
// mtb=rr&15, g=gq*8+xcd, nh=g>>2, sp=g&3 (16 mtb-blocks/group on one XCD).
// All 256 thr stage K AND V. Waves: mc=w (32-m chunk of 4).
// LDS: Ks[2][4608] | VT[2][4608] | cks[2][64]  (37376 B; x4 = 149.5KB < 160KB).
template <bool BF16>
__device__ void kv_impl(const void* K, const void* V, const void* P, const float* cws,
                        float* kvf01, float* ksum01, char* smem) {
    unsigned short* Ks = (unsigned short*)smem;            // [2][4608]
    unsigned short* VT = (unsigned short*)(smem + 18432);  // [2][4608]
    float* cks = (float*)(smem + 36864);                   // [2][64]

    const int t = threadIdx.x;
    const int w = t >> 6, ln = t & 31, hi = (t >> 5) & 1;
    const int mc = w;  // 32-m chunk in [0,4)
    const int bid = blockIdx.x;
    const int xcd = bid & 7, rr = bid >> 3;
    const int gq = rr >> 4, mtb = rr & 15;
    const int g = gq * 8 + xcd;
    const int nh = g >> 2, sp = g & 3;
    const int n = nh >> 3, h = nh & 7;
    const size_t xbase = (size_t)n * (LL * ROWSTR) + (size_t)h * 64;
    const int st0 = sp * 8;
    const int mbase = mtb * 128;
    const int ph = mtb & 7;

    short8 pb[4];
    #pragma unroll
    for (int c = 0; c < 4; ++c)
        pb[c] = row_load8<BF16>(P, (size_t)(mbase + mc * 32 + ln) * 64, 16 * c + 8 * hi);

    uint4 kA, kB, vA, vB; float ckr = 0.f;
    {
        const int s_a = st0 + ph, s_b = st0 + ((ph + 1) & 7);
        tile_load<BF16>(K, xbase + (size_t)(s_a * 64) * ROWSTR, ROWSTR, t, kA, kB);
        tile_store72(Ks, t, kA, kB);
        vt_load<BF16>(V, xbase + (size_t)(s_a * 64) * ROWSTR, t, vA, vB);
        vt_store72(VT, t, vA, vB);
        tile_load<BF16>(K, xbase + (size_t)(s_b * 64) * ROWSTR, ROWSTR, t, kA, kB);
        vt_load<BF16>(V, xbase + (size_t)(s_b * 64) * ROWSTR, t, vA, vB);
        if (t < 64) {
            cks[t] = cws[(size_t)nh * LL + s_a * 64 + t];
            ckr = cws[(size_t)nh * LL + s_b * 64 + t];
        }
    }
    wg_barrier_lds();

    f32x16 akv0 = zero16(), akv1 = zero16();
    float ks = 0.f;

    for (int i = 0; i < 8; ++i) {
        const int cur = i & 1;
        unsigned short* Kc = Ks + cur * 4608;
        unsigned short* Vc = VT + cur * 4608;
        const float* cc = cks + cur * 64;
        #pragma unroll
        for (int ss = 0; ss < 2; ++ss) {
            f32x16 D = zero16();
            #pragma unroll
            for (int c = 0; c < 4; ++c) {
                const short8 af = *(const short8*)&Kc[(32 * ss + ln) * 72 + 16 * c + 8 * hi];
                D = MFMA32(af, pb[c], D);
            }
            if (ss == 0 && i + 1 < 8) {
                tile_store72(Ks + (cur ^ 1) * 4608, t, kA, kB);
                vt_store72(VT + (cur ^ 1) * 4608, t, vA, vB);
                if (t < 64) cks[(cur ^ 1) * 64 + t] = ckr;
                if (i + 2 < 8) {
                    const int st = st0 + ((i + 2 + ph) & 7);
                    tile_load<BF16>(K, xbase + (size_t)(st * 64) * ROWSTR, ROWSTR, t, kA, kB);
                    vt_load<BF16>(V, xbase + (size_t)(st * 64) * ROWSTR, t, vA, vB);
                    if (t < 64) ckr = cws[(size_t)nh * LL + st * 64 + t];
                }
            }
            unsigned int pd[8];
            #pragma unroll
            for (int gIdx = 0; gIdx < 4; ++gIdx) {
                const float4 c4 = *(const float4*)&cc[32 * ss + 8 * gIdx + 4 * hi];
                const float ca[4] = {c4.x, c4.y, c4.z, c4.w};
                float f[4];
                #pragma unroll
                for (int b = 0; b < 4; ++b) {
                    const float arg = fminf(fmaf(D[4 * gIdx + b], NORMC2, -ca[b]), 0.f);
                    f[b] = fmaf(__builtin_amdgcn_exp2f(arg), RATIO, REPS);
                }
                ks += (f[0] + f[1]) + (f[2] + f[3]);
                pd[2 * gIdx] = pk2(f[0], f[1]);
                pd[2 * gIdx + 1] = pk2(f[2], f[3]);
            }
            #pragma unroll
            for (int cp = 0; cp < 2; ++cp) {
                const short8 bf = xfrag(pd, cp, hi);
                const int scol = 32 * ss + 16 * cp + 8 * hi;
                const short8 v0 = *(const short8*)&Vc[ln * 72 + scol];
                const short8 v1 = *(const short8*)&Vc[(32 + ln) * 72 + scol];
                akv0 = MFMA32(v0, bf, akv0);
                akv1 = MFMA32(v1, bf, akv1);
            }
        }
        wg_barrier_lds();
    }
    {
        ks += __shfl_xor(ks, 32);
        const int m = mbase + mc * 32 + ln;
        if (hi == 0)
            ksum01[(size_t)sp * RSPLIT + (size_t)nh * MM + m] = ks;
        float* basep = kvf01 + (size_t)sp * KVSPLIT + (size_t)nh * (size_t)(64 * MM) + m;
        #pragma unroll
        for (int r = 0; r < 16; ++r) {
            const int e = (r & 3) + 8 * (r >> 2) + 4 * hi;
            basep[(size_t)e * MM] = akv0[r];
            basep[(size_t)(e + 32) * MM] = akv1[r];
        }
    }
}

__global__ __launch_bounds__(256, 4) void LinearAttention_15985868276494_kv(
        const void* K, const void* V, const void* P, const float* flag,
        const float* cws, float* kvf01, float* ksum01) {
    extern __shared__ char smem_kv[];
    if (*flag != 0.f) kv_impl<true>(K, V, P, cws, kvf01, ksum01, smem_kv);
    else kv_impl<false>(K, V, P, cws, kvf01, ksum01, smem_kv);
}

// ---------------- reduce: kvT bf16 = sum of 4 splits; ksumW ----------------
__global__ __launch_bounds__(256) void LinearAttention_15985868276494_reduce(
        const float* __restrict__ kvf01, const float* __restrict__ ksum01,
        unsigned short* __restrict__ kvT, float* __restrict__ ksumW) {
    const int gid = blockIdx.x * 256 + threadIdx.x;
    const size_t i4 = (size_t)gid * 4;
    const float4 a = *(const float4*)&kvf01[i4];
    const float4 b = *(const float4*)&kvf01[KVSPLIT + i4];
    const float4 c = *(const float4*)&kvf01[2 * (size_t)KVSPLIT + i4];
    const float4 d = *(const float4*)&kvf01[3 * (size_t)KVSPLIT + i4];
    uint2 o;
    o.x = (unsigned)f2bf(a.x + b.x + c.x + d.x) | ((unsigned)f2bf(a.y + b.y + c.y + d.y) << 16);
    o.y = (unsigned)f2bf(a.z + b.z + c.z + d.z) | ((unsigned)f2bf(a.w + b.w + c.w + d.w) << 16);
    *(uint2*)&kvT[i4] = o;
    if (blockIdx.x < 32) {
        const float4 e = *(const float4*)&ksum01[i4];
        const float4 f = *(const float4*)&ksum01[RSPLIT + i4];
        const float4 g = *(const float4*)&ksum01[2 * RSPLIT + i4];
        const float4 h = *(const float4*)&ksum01[3 * RSPLIT + i4];
        *(float4*)&ksumW[i4] = make_float4(e.x + f.x + g.x + h.x, e.y + f.y + g.y + h.y,
                                           e.z + f.z + g.z + h.z, e.w + f.w + g.w + h.w);
    }
}

// ---------------- out: FINAL output, no m-split (unchanged from R19) ----------------
// 512 blocks x 512 thr, 2 blk/CU. Block owns 64 l-rows; streams all 32 m-tiles as
// 16 staggered PAIRS (ph = lbb&15). Waves: lc=w&1, mspl=(w>>1)&1, ts=w>>2.
// LDS: Ps[2][2][4608] | KVs[2][2][4608] | kss[2][128] (74240 B; x2 = 148.5KB).
template <bool BF16>
__device__ void out_impl(const void* Q, const void* P, const float* cqw,
                         const unsigned short* kvT, const float* ksum,
                         void* outp, char* smem) {
    unsigned short* Ps = (unsigned short*)smem;              // [2][2][4608]
    unsigned short* KVs = (unsigned short*)(smem + 36864);   // [2][2][4608]
    unsigned short* kss = (unsigned short*)(smem + 73728);   // [2][128]
    float* fin = (float*)smem;                               // [4*64*33] (aliases)

    const int t = threadIdx.x;
    const int w = t >> 6, ln = t & 31, hi = (t >> 5) & 1;
    const int lc = w & 1, mspl = (w >> 1) & 1, ts = w >> 2;
    const int bid = blockIdx.x;
    const int xcd = bid & 7, rr = bid >> 3;
    const int nh = xcd | ((rr & 1) << 3);
    const int lbb = rr >> 1;
    const int n = nh >> 3, h = nh & 7;
    const size_t qbase = (size_t)n * (LL * ROWSTR) + (size_t)h * 64;
    const size_t kvbase = (size_t)nh * (size_t)(64 * MM);
    const int lbase = lbb * 64;
    const int ph = lbb & 15;

    const bool stP = (t < 256);
    const int tl = t & 255;

    short8 qb[4];
    #pragma unroll
    for (int c = 0; c < 4; ++c)
        qb[c] = row_load8<BF16>(Q, qbase + (size_t)(lbase + lc * 32 + ln) * ROWSTR, 16 * c + 8 * hi);
    const float cq = cqw[(size_t)nh * LL + lbase + lc * 32 + ln];

    uint4 eA, eB, oA, oB; float ksr = 0.f;
    {
        const int p0 = ph, p1 = (ph + 1) & 15;
        if (stP) {
            tile_load<BF16>(P, (size_t)(p0 * 128) * 64, 64, tl, eA, eB);
            tile_store72(Ps, tl, eA, eB);
            tile_load<BF16>(P, (size_t)(p0 * 128 + 64) * 64, 64, tl, eA, eB);
            tile_store72(Ps + 4608, tl, eA, eB);
            tile_load<BF16>(P, (size_t)(p1 * 128) * 64, 64, tl, eA, eB);
            tile_load<BF16>(P, (size_t)(p1 * 128 + 64) * 64, 64, tl, oA, oB);
        } else {
            tile_load<true>(kvT, kvbase + p0 * 128, MM, tl, eA, eB);
            tile_store72(KVs, tl, eA, eB);
            tile_load<true>(kvT, kvbase + p0 * 128 + 64, MM, tl, eA, eB);
            tile_store72(KVs + 4608, tl, eA, eB);
            tile_load<true>(kvT, kvbase + p1 * 128, MM, tl, eA, eB);
            tile_load<true>(kvT, kvbase + p1 * 128 + 64, MM, tl, oA, oB);
        }
        if (t < 128) {
            kss[t] = f2bf(ksum[(size_t)nh * MM + p0 * 128 + t]);
            ksr = ksum[(size_t)nh * MM + p1 * 128 + t];
        }
    }
    wg_barrier_lds();

    f32x16 ao0 = zero16(), ao1 = zero16(), ad = zero16();

    for (int i = 0; i < 16; ++i) {
        const int cur = i & 1;
        unsigned short* Pc = Ps + cur * 9216 + ts * 4608;
        unsigned short* Kc = KVs + cur * 9216 + ts * 4608;
        const unsigned short* ksc = kss + cur * 128 + ts * 64;
        f32x16 D = zero16();
        #pragma unroll
        for (int c = 0; c < 4; ++c) {
            const short8 af = *(const short8*)&Pc[(32 * mspl + ln) * 72 + 16 * c + 8 * hi];
            D = MFMA32(af, qb[c], D);
        }
        if (i + 1 < 16) {
            if (stP) {
                tile_store72(Ps + (cur ^ 1) * 9216, tl, eA, eB);
                tile_store72(Ps + (cur ^ 1) * 9216 + 4608, tl, oA, oB);
                if (i + 2 < 16) {
                    const int p = (i + 2 + ph) & 15;
                    tile_load<BF16>(P, (size_t)(p * 128) * 64, 64, tl, eA, eB);
                    tile_load<BF16>(P, (size_t)(p * 128 + 64) * 64, 64, tl, oA, oB);
                }
            } else {
                tile_store72(KVs + (cur ^ 1) * 9216, tl, eA, eB);
                tile_store72(KVs + (cur ^ 1) * 9216 + 4608, tl, oA, oB);
                if (i + 2 < 16) {
                    const int p = (i + 2 + ph) & 15;
                    tile_load<true>(kvT, kvbase + p * 128, MM, tl, eA, eB);
                    tile_load<true>(kvT, kvbase + p * 128 + 64, MM, tl, oA, oB);
                }
            }
            if (t < 128) {
                kss[(cur ^ 1) * 128 + t] = f2bf(ksr);
                if (i + 2 < 16) {
                    const int p = (i + 2 + ph) & 15;
                    ksr = ksum[(size_t)nh * MM + p * 128 + t];
                }
            }
        }
        unsigned int pd[8];
        #pragma unroll
        for (int gIdx = 0; gIdx < 4; ++gIdx) {
            float f[4];
            #pragma unroll
            for (int b = 0; b < 4; ++b) {
                const float arg = fminf(fmaf(D[4 * gIdx + b], NORMC2, -cq), 0.f);
                f[b] = fmaf(__builtin_amdgcn_exp2f(arg), RATIO, REPS);
            }
            pd[2 * gIdx] = pk2(f[0], f[1]);
            pd[2 * gIdx + 1] = pk2(f[2], f[3]);
        }
        #pragma unroll
        for (int cp = 0; cp < 2; ++cp) {
            const short8 bf = xfrag(pd, cp, hi);
            const int mcol = 32 * mspl + 16 * cp + 8 * hi;
            const short8 a0 = *(const short8*)&Kc[ln * 72 + mcol];
            const short8 a1 = *(const short8*)&Kc[(32 + ln) * 72 + mcol];
            const short8 k8 = *(const short8*)&ksc[mcol];
            ao0 = MFMA32(a0, bf, ao0);
            ao1 = MFMA32(a1, bf, ao1);
            ad = MFMA32(k8, bf, ad);
        }
        wg_barrier_lds();
    }
    #pragma unroll 1
    for (int e2 = 0; e2 < 2; ++e2) {
        if (lc == e2) {
            const int addr = ((mspl * 2 + ts) * 64 + (t & 63)) * 33;
            #pragma unroll
            for (int r = 0; r < 16; ++r) fin[addr + r] = ao0[r];
            #pragma unroll
            for (int r = 0; r < 16; ++r) fin[addr + 16 + r] = ao1[r];
            fin[addr + 32] = ad[0];
        }
        wg_barrier_lds();
        {
            const int l32 = t >> 4, eg = t & 15;
            const int lane_l = l32;
            float adt = 0.f;
            #pragma unroll
            for (int s = 0; s < 4; ++s) adt += fin[(s * 64 + lane_l) * 33 + 32];
            const float z = 1.0f / (adt + EPSD);
            const int l = lbase + e2 * 32 + l32;
            const size_t row = (size_t)(n * LL + l) * HH + h;
            float vals[4];
            #pragma unroll
            for (int b = 0; b < 4; ++b) {
                const int e = eg * 4 + b;
                const int t16 = e >> 5, e5 = e & 31;
                const int hi_s = (e5 >> 2) & 1;
                const int reg = 16 * t16 + (e5 & 3) + 4 * (e5 >> 3);
                const int lane_s = hi_s * 32 + lane_l;
                float o = 0.f;
                #pragma unroll
                for (int s = 0; s < 4; ++s) o += fin[(s * 64 + lane_s) * 33 + reg];
                vals[b] = o * z;
            }
            if (BF16) {
                uint2 ov;
                ov.x = (unsigned)f2bf(vals[0]) | ((unsigned)f2bf(vals[1]) << 16);
                ov.y = (unsigned)f2bf(vals[2]) | ((unsigned)f2bf(vals[3]) << 16);
                *(uint2*)((unsigned short*)outp + row * 64 + eg * 4) = ov;
            } else {
                *(float4*)((float*)outp + row * 64 + eg * 4) =
                    make_float4(vals[0], vals[1], vals[2], vals[3]);
            }
        }
        wg_barrier_lds();
    }
}

__global__ __launch_bounds__(512, 4) void LinearAttention_15985868276494_out(
        const void* Q, const void* P, const float* flag, const float* cqw,
        const unsigned short* kvT, const float* ksum, void* outp) {
    extern __shared__ char smem_out[];
    if (*flag != 0.f) out_impl<true>(Q, P, cqw, kvT, ksum, outp, smem_out);
    else out_impl<false>(Q, P, cqw, kvT, ksum, outp, smem_out);
}

extern "C" void kernel_launch(void* const* d_in, const int* in_sizes, int n_in,
                              void* d_out, int out_size, void* d_ws, size_t ws_size,
                              hipStream_t stream) {
    const void* Q = d_in[0];
    const void* K = d_in[1];
    const void* V = d_in[2];
    const void* P = d_in[3];

    float* W = (float*)d_ws;
    float* flag = W;                                  // [16]
    float* c_k = W + 16;                              // [32768]
    float* c_q = c_k + 32768;                         // [32768]
    float* ksum01 = c_q + 32768;                      // [4][32768]
    float* kvf01 = ksum01 + 4 * RSPLIT;               // [4][16][64][2048] f32
    float* ksumW = kvf01 + 4 * (size_t)KVSPLIT;       // [32768]
    unsigned short* kvTW = (unsigned short*)(ksumW + RSPLIT);  // [16][64][2048] bf16

    LinearAttention_15985868276494_detect<<<1, 64, 0, stream>>>(
        (const unsigned short*)P, flag);
    LinearAttention_15985868276494_stats<<<dim3(512, 2), 256, 18944, stream>>>(
        K, Q, P, flag, c_k, c_q);
    LinearAttention_15985868276494_kv<<<dim3(1024), 256, 37376, stream>>>(
        K, V, P, flag, c_k, kvf01, ksum01);
    LinearAttention_15985868276494_reduce<<<2048, 256, 0, stream>>>(
        kvf01, ksum01, kvTW, ksumW);
    LinearAttention_15985868276494_out<<<dim3(512), 512, 74240, stream>>>(
        Q, P, flag, c_q, kvTW, ksumW, d_out);
}

// Round 16
// 176.647 us; speedup vs baseline: 1.1204x; 1.1204x over previous
//
#include <hip/hip_runtime.h>

// Performer linear attention, 32x32x16 MFMA, register-resident features.
// n=2, l=2048, h=8, e=64, m=2048. Dtype runtime-detected (bf16 confirmed).
// ws (floats): flag[16] | c_k[32768] | c_q[32768] | ksum01[4][32768] | kvf01[4][16][64][2048]
//   f32 | ksumW[32768] | kvT bf16[16][64][2048]
// R22 = exact resubmit of the verified-best R19 build (176.9us, passed, absmax 0.0029).
//     R21's run died on container acquisition (no kernel signal). Structure: stats/kv
//     512-thr 2blk/CU staggered (R17), kv 4-way sp-split + direct epilogue (R15),
//     out fused final-output 8-role pairs (R19), reduce 4-way fan-in.

#define LL 2048
#define HH 8
#define MM 2048
#define ROWSTR 512  // HH*64

#define NORMC 0.35355339059327373f   // 64^-0.25
#define LOG2E 1.4426950408889634f
#define NORMC2 (NORMC * LOG2E)
#define RATIO 0.022097086912079608f  // 2048^-0.5
#define KEPS 1e-4f
#define REPS (RATIO * KEPS)
#define EPSD 1e-6f

#define KVSPLIT 2097152
#define RSPLIT 32768

typedef __attribute__((ext_vector_type(8))) short short8;
typedef __attribute__((ext_vector_type(16))) float f32x16;

#define MFMA32(a, b, c) __builtin_amdgcn_mfma_f32_32x32x16_bf16((a), (b), (c), 0, 0, 0)

// LDS-only workgroup barrier: drains lgkmcnt but leaves global loads in flight.
__device__ __forceinline__ void wg_barrier_lds() {
    asm volatile("s_waitcnt lgkmcnt(0)" ::: "memory");
    __builtin_amdgcn_s_barrier();
    __builtin_amdgcn_sched_barrier(0);
}

__device__ __forceinline__ f32x16 zero16() {
    f32x16 v;
    #pragma unroll
    for (int i = 0; i < 16; ++i) v[i] = 0.f;
    return v;
}
__device__ __forceinline__ unsigned short f2bf(float f) {  // RNE
    union { float f; unsigned int u; } v; v.f = f;
    unsigned int r = v.u + 0x7fffu + ((v.u >> 16) & 1u);
    return (unsigned short)(r >> 16);
}
__device__ __forceinline__ unsigned int pk2(float lo, float hi) {  // trunc pack
    return __builtin_amdgcn_perm(__float_as_uint(hi), __float_as_uint(lo), 0x07060302u);
}
__device__ __forceinline__ float bf2f(unsigned short u) {
    union { unsigned int ui; float f; } v; v.ui = ((unsigned int)u) << 16; return v.f;
}

// ---- direct global row-fragment load: 8 bf16 at row*stride + off ----
template <bool BF16>
__device__ __forceinline__ short8 row_load8(const void* src, size_t rowbase, int off) {
    if (BF16) {
        return *(const short8*)((const unsigned short*)src + rowbase + off);
    } else {
        const float* p = (const float*)src + rowbase + off;
        float4 f0 = ((const float4*)p)[0], f1 = ((const float4*)p)[1];
        union { unsigned int u[4]; short8 s; } v;
        v.u[0] = pk2(f0.x, f0.y); v.u[1] = pk2(f0.z, f0.w);
        v.u[2] = pk2(f1.x, f1.y); v.u[3] = pk2(f1.z, f1.w);
        return v.s;
    }
}

// ---- 64x64 tile staging into LDS [64][72] bf16 (256-thread pattern) ----
template <bool BF16>
__device__ __forceinline__ void tile_load(const void* src, size_t base, size_t rstride,
                                          int t, uint4& A, uint4& B) {
    const int row = t >> 2, c16 = (t & 3) * 16;
    if (BF16) {
        const unsigned short* p = (const unsigned short*)src + base + (size_t)row * rstride + c16;
        A = *(const uint4*)p;
        B = *(const uint4*)(p + 8);
    } else {
        const float* p = (const float*)src + base + (size_t)row * rstride + c16;
        float4 f0 = ((const float4*)p)[0], f1 = ((const float4*)p)[1];
        float4 f2 = ((const float4*)p)[2], f3 = ((const float4*)p)[3];
        A.x = pk2(f0.x, f0.y); A.y = pk2(f0.z, f0.w);
        A.z = pk2(f1.x, f1.y); A.w = pk2(f1.z, f1.w);
        B.x = pk2(f2.x, f2.y); B.y = pk2(f2.z, f2.w);
        B.z = pk2(f3.x, f3.y); B.w = pk2(f3.z, f3.w);
    }
}
__device__ __forceinline__ void tile_store72(unsigned short* D, int t, uint4 A, uint4 B) {
    const int row = t >> 2, c16 = (t & 3) * 16;
    *(uint4*)&D[row * 72 + c16] = A;
    *(uint4*)&D[row * 72 + c16 + 8] = B;
}

// ---- V transpose staging into LDS [64e][72] (256-thread pattern) ----
template <bool BF16>
__device__ __forceinline__ void vt_load(const void* V, size_t base, int t, uint4& A, uint4& B) {
    const int s0 = (t & 31) * 2, e0 = (t >> 5) * 8;
    if (BF16) {
        const unsigned short* p = (const unsigned short*)V + base + (size_t)s0 * ROWSTR + e0;
        A = *(const uint4*)p;
        B = *(const uint4*)(p + ROWSTR);
    } else {
        const float* p = (const float*)V + base + (size_t)s0 * ROWSTR + e0;
        float4 f0 = ((const float4*)p)[0], f1 = ((const float4*)p)[1];
        const float* q = p + ROWSTR;
        float4 g0 = ((const float4*)q)[0], g1 = ((const float4*)q)[1];
        A.x = pk2(f0.x, f0.y); A.y = pk2(f0.z, f0.w);
        A.z = pk2(f1.x, f1.y); A.w = pk2(f1.z, f1.w);
        B.x = pk2(g0.x, g0.y); B.y = pk2(g0.z, g0.w);
        B.z = pk2(g1.x, g1.y); B.w = pk2(g1.z, g1.w);
    }
}
__device__ __forceinline__ void vt_store72(unsigned short* VT, int t, uint4 A, uint4 B) {
    const int s0 = (t & 31) * 2, e0 = (t >> 5) * 8;
    const unsigned ua[4] = {A.x, A.y, A.z, A.w}, ub[4] = {B.x, B.y, B.z, B.w};
    #pragma unroll
    for (int i = 0; i < 4; ++i) {
        *(unsigned*)&VT[(e0 + 2 * i) * 72 + s0] = (ua[i] & 0xFFFFu) | (ub[i] << 16);
        *(unsigned*)&VT[(e0 + 2 * i + 1) * 72 + s0] = (ua[i] >> 16) | (ub[i] & 0xFFFF0000u);
    }
}

// ---- D-layout -> B-operand exchange (half-wave) ----
__device__ __forceinline__ short8 xfrag(const unsigned int pd[8], int cp, int hi) {
    const unsigned int s0 = hi ? pd[4 * cp + 0] : pd[4 * cp + 2];
    const unsigned int s1 = hi ? pd[4 * cp + 1] : pd[4 * cp + 3];
    const unsigned int r0 = (unsigned int)__shfl_xor((int)s0, 32);
    const unsigned int r1 = (unsigned int)__shfl_xor((int)s1, 32);
    union { unsigned int u[4]; short8 s; } v;
    v.u[0] = hi ? r0 : pd[4 * cp + 0];
    v.u[1] = hi ? r1 : pd[4 * cp + 1];
    v.u[2] = hi ? pd[4 * cp + 2] : r0;
    v.u[3] = hi ? pd[4 * cp + 3] : r1;
    return v.s;
}

// ---------------- dtype detection ----------------
__global__ void LinearAttention_15985868276494_detect(const unsigned short* __restrict__ P,
                                                      float* __restrict__ flag) {
    if (threadIdx.x == 0) {
        int sane = 1;
        #pragma unroll
        for (int i = 0; i < 16; ++i) {
            const unsigned e = (P[2 * i] >> 7) & 0xFF;
            if (e < 101 || e > 141) sane = 0;
        }
        *flag = sane ? 1.0f : 0.0f;
    }
}

// ---------------- stats: c[nh][l]*log2e, 128 rows/block, 32 P-tile stream ----------------
// 512 blocks x 512 thr (8 waves), 2 blk/CU, staggered ph = bid&31.
template <bool BF16>
__device__ void stats_impl(const void* X, const void* P, float* cws, char* smem) {
    unsigned short* Ps = (unsigned short*)smem;        // [2][4608]
    float* red = (float*)(smem + 18432);               // [256]
    const int t = threadIdx.x;
    const int w = t >> 6, ln = t & 31, hi = (t >> 5) & 1;
    const int mstrip = w & 1, r3 = w >> 1;
    const int row_base = blockIdx.x * 128;
    const int ph = blockIdx.x & 31;

    short8 xb[4];
    #pragma unroll
    for (int c = 0; c < 4; ++c)
        xb[c] = row_load8<BF16>(X, (size_t)(row_base + r3 * 32 + ln) * 64, 16 * c + 8 * hi);

    const bool stP = (t < 256);
    const int tl = t & 255;
    uint4 pA, pB;
    if (stP) {
        uint4 a0, b0;
        tile_load<BF16>(P, (size_t)(ph * 64) * 64, 64, tl, a0, b0);
        tile_store72(Ps, tl, a0, b0);
        tile_load<BF16>(P, (size_t)(((ph + 1) & 31) * 64) * 64, 64, tl, pA, pB);
    }
    wg_barrier_lds();

    float rmax = -3e38f;
    for (int i = 0; i < 32; ++i) {
        const int cur = i & 1;
        unsigned short* Pc = Ps + cur * 4608;
        f32x16 acc = zero16();
        #pragma unroll
        for (int c = 0; c < 4; ++c) {
            const short8 af = *(const short8*)&Pc[(32 * mstrip + ln) * 72 + 16 * c + 8 * hi];
            acc = MFMA32(af, xb[c], acc);
        }
        if (stP && i + 1 < 32) {
            tile_store72(Ps + (cur ^ 1) * 4608, tl, pA, pB);
            if (i + 2 < 32)
                tile_load<BF16>(P, (size_t)(((i + 2 + ph) & 31) * 64) * 64, 64, tl, pA, pB);
        }
        #pragma unroll
        for (int r = 0; r < 16; ++r) rmax = fmaxf(rmax, acc[r]);
        wg_barrier_lds();
    }
    rmax = fmaxf(rmax, __shfl_xor(rmax, 32));
    if (hi == 0) red[w * 32 + ln] = rmax;
    float s2 = 0.f;
    if (mstrip == 0) {
        #pragma unroll
        for (int c = 0; c < 4; ++c) {
            union { short8 s; unsigned int u[4]; } uv; uv.s = xb[c];
            #pragma unroll
            for (int i2 = 0; i2 < 4; ++i2) {
                const float lo = bf2f((unsigned short)(uv.u[i2] & 0xFFFF));
                const float hv = bf2f((unsigned short)(uv.u[i2] >> 16));
                s2 = fmaf(lo, lo, s2); s2 = fmaf(hv, hv, s2);
            }
        }
        s2 += __shfl_xor(s2, 32);
    }
    wg_barrier_lds();
    if (mstrip == 0 && hi == 0) {
        const float rm = fmaxf(red[w * 32 + ln], red[(w + 1) * 32 + ln]);
        const int rg = row_base + r3 * 32 + ln;
        const int n = rg >> 14, l = (rg >> 3) & 2047, h = rg & 7;
        cws[(size_t)((n << 3) | h) * LL + l] =
            (NORMC * rm + (0.5f * NORMC * NORMC) * s2) * LOG2E;
    }
}

__global__ __launch_bounds__(512, 4) void LinearAttention_15985868276494_stats(
        const void* K, const void* Q, const void* P, const float* flag,
        float* c_k, float* c_q) {
    extern __shared__ char smem_st[];
    const void* X = (blockIdx.y == 0) ? K : Q;
    float* cws = (blockIdx.y == 0) ? c_k : c_q;
    if (*flag != 0.f) stats_impl<true>(X, P, cws, smem_st);
    else stats_impl<false>(X, P, cws, smem_st);
}

// ---------------- kv: partial kvf[sp][nh][e][m] f32, ksum01 (sp in 0..3) ----------------
// 512 blocks x 512 thr, 2 blk/CU, staggered ph = mtb&7 (T=8).
template <bool BF16>
__device__ void kv_impl(const void* K, const void* V, const void* P, const float* cws,
                        float* kvf01, float* ksum01, char* smem) {
    unsigned short* Ks = (unsigned short*)smem;            // [2][4608]
    unsigned short* VT = (unsigned short*)(smem + 18432);  // [2][4608]
    float* cks = (float*)(smem + 36864);                   // [2][64]

    const int t = threadIdx.x;
    const int w = t >> 6, ln = t & 31, hi = (t >> 5) & 1;
    const int mc = w;  // 32-m chunk in [0,8)
    const int bid = blockIdx.x;
    const int xcd = bid & 7, rr = bid >> 3;
    const int gq = rr >> 3, mtb = rr & 7;
    const int g = gq * 8 + xcd;
    const int nh = g >> 2, sp = g & 3;
    const int n = nh >> 3, h = nh & 7;
    const size_t xbase = (size_t)n * (LL * ROWSTR) + (size_t)h * 64;
    const int st0 = sp * 8;
    const int mbase = mtb * 256;
    const int ph = mtb & 7;

    const bool stK = (t < 256);
    const int tl = t & 255;

    short8 pb[4];
    #pragma unroll
    for (int c = 0; c < 4; ++c)
        pb[c] = row_load8<BF16>(P, (size_t)(mbase + mc * 32 + ln) * 64, 16 * c + 8 * hi);

    uint4 kA, kB, vA, vB; float ckr = 0.f;
    {
        const int s_a = st0 + ph, s_b = st0 + ((ph + 1) & 7);
        if (stK) {
            tile_load<BF16>(K, xbase + (size_t)(s_a * 64) * ROWSTR, ROWSTR, tl, kA, kB);
            tile_store72(Ks, tl, kA, kB);
            tile_load<BF16>(K, xbase + (size_t)(s_b * 64) * ROWSTR, ROWSTR, tl, kA, kB);
        } else {
            vt_load<BF16>(V, xbase + (size_t)(s_a * 64) * ROWSTR, tl, vA, vB);
            vt_store72(VT, tl, vA, vB);
            vt_load<BF16>(V, xbase + (size_t)(s_b * 64) * ROWSTR, tl, vA, vB);
        }
        if (t < 64) {
            cks[t] = cws[(size_t)nh * LL + s_a * 64 + t];
            ckr = cws[(size_t)nh * LL + s_b * 64 + t];
        }
    }
    wg_barrier_lds();

    f32x16 akv0 = zero16(), akv1 = zero16();
    float ks = 0.f;

    for (int i = 0; i < 8; ++i) {
        const int cur = i & 1;
        unsigned short* Kc = Ks + cur * 4608;
        unsigned short* Vc = VT + cur * 4608;
        const float* cc = cks + cur * 64;
        #pragma unroll
        for (int ss = 0; ss < 2; ++ss) {
            f32x16 D = zero16();
            #pragma unroll
            for (int c = 0; c < 4; ++c) {
                const short8 af = *(const short8*)&Kc[(32 * ss + ln) * 72 + 16 * c + 8 * hi];
                D = MFMA32(af, pb[c], D);
            }
            if (ss == 0 && i + 1 < 8) {
                if (stK) tile_store72(Ks + (cur ^ 1) * 4608, tl, kA, kB);
                else vt_store72(VT + (cur ^ 1) * 4608, tl, vA, vB);
                if (t < 64) cks[(cur ^ 1) * 64 + t] = ckr;
                if (i + 2 < 8) {
                    const int st = st0 + ((i + 2 + ph) & 7);
                    if (stK) tile_load<BF16>(K, xbase + (size_t)(st * 64) * ROWSTR, ROWSTR, tl, kA, kB);
                    else vt_load<BF16>(V, xbase + (size_t)(st * 64) * ROWSTR, tl, vA, vB);
                    if (t < 64) ckr = cws[(size_t)nh * LL + st * 64 + t];
                }
            }
            unsigned int pd[8];
            #pragma unroll
            for (int gIdx = 0; gIdx < 4; ++gIdx) {
                const float4 c4 = *(const float4*)&cc[32 * ss + 8 * gIdx + 4 * hi];
                const float ca[4] = {c4.x, c4.y, c4.z, c4.w};
                float f[4];
                #pragma unroll
                for (int b = 0; b < 4; ++b) {
                    const float arg = fminf(fmaf(D[4 * gIdx + b], NORMC2, -ca[b]), 0.f);
                    f[b] = fmaf(__builtin_amdgcn_exp2f(arg), RATIO, REPS);
                }
                ks += (f[0] + f[1]) + (f[2] + f[3]);
                pd[2 * gIdx] = pk2(f[0], f[1]);
                pd[2 * gIdx + 1] = pk2(f[2], f[3]);
            }
            #pragma unroll
            for (int cp = 0; cp < 2; ++cp) {
                const short8 bf = xfrag(pd, cp, hi);
                const int scol = 32 * ss + 16 * cp + 8 * hi;
                const short8 v0 = *(const short8*)&Vc[ln * 72 + scol];
                const short8 v1 = *(const short8*)&Vc[(32 + ln) * 72 + scol];
                akv0 = MFMA32(v0, bf, akv0);
                akv1 = MFMA32(v1, bf, akv1);
            }
        }
        wg_barrier_lds();
    }
    {
        ks += __shfl_xor(ks, 32);
        const int m = mbase + mc * 32 + ln;
        if (hi == 0)
            ksum01[(size_t)sp * RSPLIT + (size_t)nh * MM + m] = ks;
        float* basep = kvf01 + (size_t)sp * KVSPLIT + (size_t)nh * (size_t)(64 * MM) + m;
        #pragma unroll
        for (int r = 0; r < 16; ++r) {
            const int e = (r & 3) + 8 * (r >> 2) + 4 * hi;
            basep[(size_t)e * MM] = akv0[r];
            basep[(size_t)(e + 32) * MM] = akv1[r];
        }
    }
}

__global__ __launch_bounds__(512, 4) void LinearAttention_15985868276494_kv(
        const void* K, const void* V, const void* P, const float* flag,
        const float* cws, float* kvf01, float* ksum01) {
    extern __shared__ char smem_kv[];
    if (*flag != 0.f) kv_impl<true>(K, V, P, cws, kvf01, ksum01, smem_kv);
    else kv_impl<false>(K, V, P, cws, kvf01, ksum01, smem_kv);
}

// ---------------- reduce: kvT bf16 = sum of 4 splits; ksumW ----------------
__global__ __launch_bounds__(256) void LinearAttention_15985868276494_reduce(
        const float* __restrict__ kvf01, const float* __restrict__ ksum01,
        unsigned short* __restrict__ kvT, float* __restrict__ ksumW) {
    const int gid = blockIdx.x * 256 + threadIdx.x;
    const size_t i4 = (size_t)gid * 4;
    const float4 a = *(const float4*)&kvf01[i4];
    const float4 b = *(const float4*)&kvf01[KVSPLIT + i4];
    const float4 c = *(const float4*)&kvf01[2 * (size_t)KVSPLIT + i4];
    const float4 d = *(const float4*)&kvf01[3 * (size_t)KVSPLIT + i4];
    uint2 o;
    o.x = (unsigned)f2bf(a.x + b.x + c.x + d.x) | ((unsigned)f2bf(a.y + b.y + c.y + d.y) << 16);
    o.y = (unsigned)f2bf(a.z + b.z + c.z + d.z) | ((unsigned)f2bf(a.w + b.w + c.w + d.w) << 16);
    *(uint2*)&kvT[i4] = o;
    if (blockIdx.x < 32) {
        const float4 e = *(const float4*)&ksum01[i4];
        const float4 f = *(const float4*)&ksum01[RSPLIT + i4];
        const float4 g = *(const float4*)&ksum01[2 * RSPLIT + i4];
        const float4 h = *(const float4*)&ksum01[3 * RSPLIT + i4];
        *(float4*)&ksumW[i4] = make_float4(e.x + f.x + g.x + h.x, e.y + f.y + g.y + h.y,
                                           e.z + f.z + g.z + h.z, e.w + f.w + g.w + h.w);
    }
}

// ---------------- out: FINAL output, no m-split ----------------
// 512 blocks x 512 thr, 2 blk/CU. Block owns 64 l-rows; streams all 32 m-tiles as
// 16 staggered PAIRS (ph = lbb&15). Decode: xcd=bid&7, rr=bid>>3, nh=xcd|((rr&1)<<3),
// lbb=rr>>1 (nh pinned to one XCD). Waves: lc=w&1 (32-row chunk), mspl=(w>>1)&1
// (m-strip), ts=w>>2 (pair member). fin epilogue sums 4 (mspl x ts) partials per row,
// normalizes, writes final output (bf16 or f32). No po/pad/out2.
// LDS: Ps[2][2][4608] | KVs[2][2][4608] | kss[2][128] (74240 B; x2 = 148.5KB < 160KB).
template <bool BF16>
__device__ void out_impl(const void* Q, const void* P, const float* cqw,
                         const unsigned short* kvT, const float* ksum,
                         void* outp, char* smem) {
    unsigned short* Ps = (unsigned short*)smem;              // [2][2][4608]
    unsigned short* KVs = (unsigned short*)(smem + 36864);   // [2][2][4608]
    unsigned short* kss = (unsigned short*)(smem + 73728);   // [2][128]
    float* fin = (float*)smem;                               // [4*64*33] = 33792 B (aliases)

    const int t = threadIdx.x;
    const int w = t >> 6, ln = t & 31, hi = (t >> 5) & 1;
    const int lc = w & 1, mspl = (w >> 1) & 1, ts = w >> 2;
    const int bid = blockIdx.x;
    const int xcd = bid & 7, rr = bid >> 3;
    const int nh = xcd | ((rr & 1) << 3);
    const int lbb = rr >> 1;
    const int n = nh >> 3, h = nh & 7;
    const size_t qbase = (size_t)n * (LL * ROWSTR) + (size_t)h * 64;
    const size_t kvbase = (size_t)nh * (size_t)(64 * MM);
    const int lbase = lbb * 64;
    const int ph = lbb & 15;

    const bool stP = (t < 256);
    const int tl = t & 255;

    // Q fragments direct from global (rows l = lbase + lc*32 + ln)
    short8 qb[4];
    #pragma unroll
    for (int c = 0; c < 4; ++c)
        qb[c] = row_load8<BF16>(Q, qbase + (size_t)(lbase + lc * 32 + ln) * ROWSTR, 16 * c + 8 * hi);
    const float cq = cqw[(size_t)nh * LL + lbase + lc * 32 + ln];

    uint4 eA, eB, oA, oB; float ksr = 0.f;
    {
        const int p0 = ph, p1 = (ph + 1) & 15;
        if (stP) {
            tile_load<BF16>(P, (size_t)(p0 * 128) * 64, 64, tl, eA, eB);
            tile_store72(Ps, tl, eA, eB);
            tile_load<BF16>(P, (size_t)(p0 * 128 + 64) * 64, 64, tl, eA, eB);
            tile_store72(Ps + 4608, tl, eA, eB);
            tile_load<BF16>(P, (size_t)(p1 * 128) * 64, 64, tl, eA, eB);
            tile_load<BF16>(P, (size_t)(p1 * 128 + 64) * 64, 64, tl, oA, oB);
        } else {
            tile_load<true>(kvT, kvbase + p0 * 128, MM, tl, eA, eB);
            tile_store72(KVs, tl, eA, eB);
            tile_load<true>(kvT, kvbase + p0 * 128 + 64, MM, tl, eA, eB);
            tile_store72(KVs + 4608, tl, eA, eB);
            tile_load<true>(kvT, kvbase + p1 * 128, MM, tl, eA, eB);
            tile_load<true>(kvT, kvbase + p1 * 128 + 64, MM, tl, oA, oB);
        }
        if (t < 128) {
            kss[t] = f2bf(ksum[(size_t)nh * MM + p0 * 128 + t]);
            ksr = ksum[(size_t)nh * MM + p1 * 128 + t];
        }
    }
    wg_barrier_lds();

    f32x16 ao0 = zero16(), ao1 = zero16(), ad = zero16();

    for (int i = 0; i < 16; ++i) {
        const int cur = i & 1;
        unsigned short* Pc = Ps + cur * 9216 + ts * 4608;
        unsigned short* Kc = KVs + cur * 9216 + ts * 4608;
        const unsigned short* ksc = kss + cur * 128 + ts * 64;
        // gemm1: D[m][l] for this wave's (pair member ts, m-strip mspl)
        f32x16 D = zero16();
        #pragma unroll
        for (int c = 0; c < 4; ++c) {
            const short8 af = *(const short8*)&Pc[(32 * mspl + ln) * 72 + 16 * c + 8 * hi];
            D = MFMA32(af, qb[c], D);
        }
        // staging: store pair i+1, prefetch pair i+2
        if (i + 1 < 16) {
            if (stP) {
                tile_store72(Ps + (cur ^ 1) * 9216, tl, eA, eB);
                tile_store72(Ps + (cur ^ 1) * 9216 + 4608, tl, oA, oB);
                if (i + 2 < 16) {
                    const int p = (i + 2 + ph) & 15;
                    tile_load<BF16>(P, (size_t)(p * 128) * 64, 64, tl, eA, eB);
                    tile_load<BF16>(P, (size_t)(p * 128 + 64) * 64, 64, tl, oA, oB);
                }
            } else {
                tile_store72(KVs + (cur ^ 1) * 9216, tl, eA, eB);
                tile_store72(KVs + (cur ^ 1) * 9216 + 4608, tl, oA, oB);
                if (i + 2 < 16) {
                    const int p = (i + 2 + ph) & 15;
                    tile_load<true>(kvT, kvbase + p * 128, MM, tl, eA, eB);
                    tile_load<true>(kvT, kvbase + p * 128 + 64, MM, tl, oA, oB);
                }
            }
            if (t < 128) {
                kss[(cur ^ 1) * 128 + t] = f2bf(ksr);
                if (i + 2 < 16) {
                    const int p = (i + 2 + ph) & 15;
                    ksr = ksum[(size_t)nh * MM + p * 128 + t];
                }
            }
        }
        // exp2 (cq depends on l = col only)
        unsigned int pd[8];
        #pragma unroll
        for (int gIdx = 0; gIdx < 4; ++gIdx) {
            float f[4];
            #pragma unroll
            for (int b = 0; b < 4; ++b) {
                const float arg = fminf(fmaf(D[4 * gIdx + b], NORMC2, -cq), 0.f);
                f[b] = fmaf(__builtin_amdgcn_exp2f(arg), RATIO, REPS);
            }
            pd[2 * gIdx] = pk2(f[0], f[1]);
            pd[2 * gIdx + 1] = pk2(f[2], f[3]);
        }
        // gemm2: O[e][l] += KV . F ; ad[.][l] += ksum . F  (this m-strip of this member)
        #pragma unroll
        for (int cp = 0; cp < 2; ++cp) {
            const short8 bf = xfrag(pd, cp, hi);
            const int mcol = 32 * mspl + 16 * cp + 8 * hi;
            const short8 a0 = *(const short8*)&Kc[ln * 72 + mcol];
            const short8 a1 = *(const short8*)&Kc[(32 + ln) * 72 + mcol];
            const short8 k8 = *(const short8*)&ksc[mcol];
            ao0 = MFMA32(a0, bf, ao0);
            ao1 = MFMA32(a1, bf, ao1);
            ad = MFMA32(k8, bf, ad);
        }
        wg_barrier_lds();
    }
    // epilogue: 2 epochs (one per lc chunk of 32 rows); sum 4 (mspl x ts) partials,
    // normalize, write FINAL output.
    #pragma unroll 1
    for (int e2 = 0; e2 < 2; ++e2) {
        if (lc == e2) {
            const int addr = ((mspl * 2 + ts) * 64 + (t & 63)) * 33;
            #pragma unroll
            for (int r = 0; r < 16; ++r) fin[addr + r] = ao0[r];
            #pragma unroll
            for (int r = 0; r < 16; ++r) fin[addr + 16 + r] = ao1[r];
            fin[addr + 32] = ad[0];
        }
        wg_barrier_lds();
        {
            // 512 threads cover 32 l-rows x 64 e (4 e per thread)
            const int l32 = t >> 4, eg = t & 15;
            const int lane_l = l32;
            float adt = 0.f;
            #pragma unroll
            for (int s = 0; s < 4; ++s) adt += fin[(s * 64 + lane_l) * 33 + 32];
            const float z = 1.0f / (adt + EPSD);
            const int l = lbase + e2 * 32 + l32;
            const size_t row = (size_t)(n * LL + l) * HH + h;
            float vals[4];
            #pragma unroll
            for (int b = 0; b < 4; ++b) {
                const int e = eg * 4 + b;
                const int t16 = e >> 5, e5 = e & 31;
                const int hi_s = (e5 >> 2) & 1;
                const int reg = 16 * t16 + (e5 & 3) + 4 * (e5 >> 3);
                const int lane_s = hi_s * 32 + lane_l;
                float o = 0.f;
                #pragma unroll
                for (int s = 0; s < 4; ++s) o += fin[(s * 64 + lane_s) * 33 + reg];
                vals[b] = o * z;
            }
            if (BF16) {
                uint2 ov;
                ov.x = (unsigned)f2bf(vals[0]) | ((unsigned)f2bf(vals[1]) << 16);
                ov.y = (unsigned)f2bf(vals[2]) | ((unsigned)f2bf(vals[3]) << 16);
                *(uint2*)((unsigned short*)outp + row * 64 + eg * 4) = ov;
            } else {
                *(float4*)((float*)outp + row * 64 + eg * 4) =
                    make_float4(vals[0], vals[1], vals[2], vals[3]);
            }
        }
        wg_barrier_lds();
    }
}

__global__ __launch_bounds__(512, 4) void LinearAttention_15985868276494_out(
        const void* Q, const void* P, const float* flag, const float* cqw,
        const unsigned short* kvT, const float* ksum, void* outp) {
    extern __shared__ char smem_out[];
    if (*flag != 0.f) out_impl<true>(Q, P, cqw, kvT, ksum, outp, smem_out);
    else out_impl<false>(Q, P, cqw, kvT, ksum, outp, smem_out);
}

extern "C" void kernel_launch(void* const* d_in, const int* in_sizes, int n_in,
                              void* d_out, int out_size, void* d_ws, size_t ws_size,
                              hipStream_t stream) {
    const void* Q = d_in[0];
    const void* K = d_in[1];
    const void* V = d_in[2];
    const void* P = d_in[3];

    float* W = (float*)d_ws;
    float* flag = W;                                  // [16]
    float* c_k = W + 16;                              // [32768]
    float* c_q = c_k + 32768;                         // [32768]
    float* ksum01 = c_q + 32768;                      // [4][32768]
    float* kvf01 = ksum01 + 4 * RSPLIT;               // [4][16][64][2048] f32
    float* ksumW = kvf01 + 4 * (size_t)KVSPLIT;       // [32768]
    unsigned short* kvTW = (unsigned short*)(ksumW + RSPLIT);  // [16][64][2048] bf16

    LinearAttention_15985868276494_detect<<<1, 64, 0, stream>>>(
        (const unsigned short*)P, flag);
    LinearAttention_15985868276494_stats<<<dim3(256, 2), 512, 19456, stream>>>(
        K, Q, P, flag, c_k, c_q);
    LinearAttention_15985868276494_kv<<<dim3(512), 512, 37376, stream>>>(
        K, V, P, flag, c_k, kvf01, ksum01);
    LinearAttention_15985868276494_reduce<<<2048, 256, 0, stream>>>(
        kvf01, ksum01, kvTW, ksumW);
    LinearAttention_15985868276494_out<<<dim3(512), 512, 74240, stream>>>(
        Q, P, flag, c_q, kvTW, ksumW, d_out);
}